// Round 8
// baseline (2188.302 us; speedup 1.0000x reference)
//
#include <hip/hip_runtime.h>
#include <stdint.h>

// Problem constants (fixed by the reference)
#define BROWS 8192
#define DIN   768
#define DLAT  12288
#define KTOP  64

#define LO_SCALE 4096.0f      // 2^12: keeps fp16 lo-terms normal
#define LO_INV   (1.0f / 4096.0f)

// np-association model ledger (knife rows A, B are the only discriminators):
//   exact fp64 ranking      (r3): A=wrong-side, B=?      -> np has fp32 error
//   384+384 seq chains      (r4): A=match, B=wrong       -> not bitwise np
//   320/224/224 seq chains  (r5): A=wrong
//   384 even/odd 2-acc      (r6): A=wrong
//   r4 + high-index tiebreak(r7): identical to r4        -> NO bitwise ties;
//                                 B is a value-ranking miss, tiebreak moot.
// => OpenBLAS-Haswell model (r4) is NOT np bitwise. This round: Model 1 —
//    SINGLE sequential fmaf chain over all k in [0,768), + bias last
//    (oneDNN/brgemm full-K register accumulation; MKL small-K; einsum-style).

typedef _Float16 half8 __attribute__((ext_vector_type(8)));  // 8 x fp16 (4 VGPRs)
typedef __attribute__((ext_vector_type(4))) float float4v;   // 4 x fp32 acc

typedef __attribute__((address_space(3))) void lds_void_t;
typedef __attribute__((address_space(1))) void glob_void_t;

__device__ __forceinline__ unsigned short f2h_bits(float f) {
  _Float16 h = (_Float16)f;          // RNE
  return __builtin_bit_cast(unsigned short, h);
}
__device__ __forceinline__ float h_bits_to_f(unsigned short b) {
  return (float)__builtin_bit_cast(_Float16, b);
}

// ---- x [8192,768] fp32 -> (Xh, Xl) fp16 split; lo scaled by 2^12 ----------
__global__ __launch_bounds__(256) void k_cvt_split(const float* __restrict__ in,
                                                   unsigned short* __restrict__ hi,
                                                   unsigned short* __restrict__ lo,
                                                   int n4) {
  int i = blockIdx.x * 256 + threadIdx.x;
  if (i >= n4) return;
  float4 v = ((const float4*)in)[i];
  ushort4 h, l;
  h.x = f2h_bits(v.x); l.x = f2h_bits((v.x - h_bits_to_f(h.x)) * LO_SCALE);
  h.y = f2h_bits(v.y); l.y = f2h_bits((v.y - h_bits_to_f(h.y)) * LO_SCALE);
  h.z = f2h_bits(v.z); l.z = f2h_bits((v.z - h_bits_to_f(h.z)) * LO_SCALE);
  h.w = f2h_bits(v.w); l.w = f2h_bits((v.w - h_bits_to_f(h.w)) * LO_SCALE);
  ((ushort4*)hi)[i] = h;
  ((ushort4*)lo)[i] = l;
}

// ---- W_enc [768,12288] fp32 -> Wt_hi/Wt_lo [12288,768] fp16 (transpose+split)
__global__ __launch_bounds__(256) void k_transpose_split(const float* __restrict__ W,
                                                         unsigned short* __restrict__ Wth,
                                                         unsigned short* __restrict__ Wtl) {
  __shared__ float s[32][33];
  const int n0 = blockIdx.x * 32;
  const int k0 = blockIdx.y * 32;
  const int tx = threadIdx.x, ty = threadIdx.y;  // 32 x 8
#pragma unroll
  for (int i = 0; i < 4; i++)
    s[ty + 8 * i][tx] = W[(size_t)(k0 + ty + 8 * i) * DLAT + n0 + tx];
  __syncthreads();
#pragma unroll
  for (int i = 0; i < 4; i++) {
    int nl = ty + 8 * i;
    float v = s[tx][nl];
    unsigned short h = f2h_bits(v);
    unsigned short l = f2h_bits((v - h_bits_to_f(h)) * LO_SCALE);
    size_t o = (size_t)(n0 + nl) * DIN + k0 + tx;
    Wth[o] = h;
    Wtl[o] = l;
  }
}

// ---- encoder GEMM: H = X * Wt^T + b_enc, fp16 2-term split ------------------
#define BM 128
#define BN 128
#define BK 32
__global__ __launch_bounds__(256) void k_enc_gemm(const unsigned short* __restrict__ Xh,
                                                  const unsigned short* __restrict__ Xl,
                                                  const unsigned short* __restrict__ Wth,
                                                  const unsigned short* __restrict__ Wtl,
                                                  const float* __restrict__ b_enc,
                                                  float* __restrict__ H) {
  __shared__ __align__(16) unsigned short Ah[BM * BK];
  __shared__ __align__(16) unsigned short Al[BM * BK];
  __shared__ __align__(16) unsigned short Bh[BN * BK];
  __shared__ __align__(16) unsigned short Bl[BN * BK];
  const int tid  = threadIdx.x;
  const int lane = tid & 63;
  const int wave = tid >> 6;
  const int wm = wave & 1, wn = wave >> 1;
  const int m_blk = blockIdx.y * BM;
  const int n_blk = blockIdx.x * BN;

  float4v acc1[4][4];  // hi*hi
  float4v acc2[4][4];  // hi*lo + lo*hi  (carries 2^12)
#pragma unroll
  for (int i = 0; i < 4; i++)
#pragma unroll
    for (int j = 0; j < 4; j++) { acc1[i][j] = (float4v)0.0f; acc2[i][j] = (float4v)0.0f; }

  const int srow  = lane >> 2;
  const int scol8 = (lane & 3) * 8;

  for (int kk = 0; kk < DIN; kk += BK) {
#pragma unroll
    for (int c = 0; c < 2; c++) {
      const int chunk = 2 * wave + c;            // 0..7
      const int row = chunk * 16 + srow;
      const size_t ao = (size_t)(m_blk + row) * DIN + kk + scol8;
      const size_t bo = (size_t)(n_blk + row) * DIN + kk + scol8;
      __builtin_amdgcn_global_load_lds((glob_void_t*)(Xh + ao),
                                       (lds_void_t*)(Ah + chunk * 512), 16, 0, 0);
      __builtin_amdgcn_global_load_lds((glob_void_t*)(Xl + ao),
                                       (lds_void_t*)(Al + chunk * 512), 16, 0, 0);
      __builtin_amdgcn_global_load_lds((glob_void_t*)(Wth + bo),
                                       (lds_void_t*)(Bh + chunk * 512), 16, 0, 0);
      __builtin_amdgcn_global_load_lds((glob_void_t*)(Wtl + bo),
                                       (lds_void_t*)(Bl + chunk * 512), 16, 0, 0);
    }
    __syncthreads();

    half8 ah[4], al[4], bh[4], bl[4];
#pragma unroll
    for (int mi = 0; mi < 4; mi++) {
      const size_t o = (size_t)(wm * 64 + mi * 16 + (lane & 15)) * BK + (lane >> 4) * 8;
      ah[mi] = *(const half8*)(Ah + o);
      al[mi] = *(const half8*)(Al + o);
    }
#pragma unroll
    for (int ni = 0; ni < 4; ni++) {
      const size_t o = (size_t)(wn * 64 + ni * 16 + (lane & 15)) * BK + (lane >> 4) * 8;
      bh[ni] = *(const half8*)(Bh + o);
      bl[ni] = *(const half8*)(Bl + o);
    }

#pragma unroll
    for (int mi = 0; mi < 4; mi++)
#pragma unroll
      for (int ni = 0; ni < 4; ni++) {
        acc1[mi][ni] = __builtin_amdgcn_mfma_f32_16x16x32_f16(ah[mi], bh[ni], acc1[mi][ni], 0, 0, 0);
        acc2[mi][ni] = __builtin_amdgcn_mfma_f32_16x16x32_f16(al[mi], bh[ni], acc2[mi][ni], 0, 0, 0);
        acc2[mi][ni] = __builtin_amdgcn_mfma_f32_16x16x32_f16(ah[mi], bl[ni], acc2[mi][ni], 0, 0, 0);
      }
    __syncthreads();
  }

  const int col   = lane & 15;
  const int rbase = (lane >> 4) * 4;
#pragma unroll
  for (int ni = 0; ni < 4; ni++) {
    const int n = n_blk + wn * 64 + ni * 16 + col;
    const float bias = b_enc[n];
#pragma unroll
    for (int mi = 0; mi < 4; mi++) {
#pragma unroll
      for (int r = 0; r < 4; r++) {
        const int m = m_blk + wm * 64 + mi * 16 + rbase + r;
        H[(size_t)m * DLAT + n] = acc1[mi][ni][r] + acc2[mi][ni][r] * LO_INV + bias;
      }
    }
  }
}

// ---- top-64 per row with np-simulated boundary arbitration -----------------
#define UMARGIN 4e-4f
#define UCAP 64
__device__ __forceinline__ float key_to_f32(unsigned k) {
  unsigned u = (k & 0x80000000u) ? (k & 0x7fffffffu) : ~k;
  return __uint_as_float(u);
}
__global__ __launch_bounds__(256) void k_topk(float* __restrict__ Z,
                                              const float* __restrict__ x,
                                              const float* __restrict__ We,
                                              const float* __restrict__ b_enc,
                                              int* __restrict__ idxl,
                                              float* __restrict__ vall) {
  const int row = blockIdx.x;
  const int tid = threadIdx.x;
  const int lane = tid & 63, wid = tid >> 6;
  float* zr = Z + (size_t)row * DLAT;

  unsigned keys[48];
#pragma unroll
  for (int j = 0; j < 48; j++) {
    unsigned u = __float_as_uint(zr[tid + 256 * j]);
    keys[j] = (u & 0x80000000u) ? ~u : (u | 0x80000000u);
  }

  __shared__ int wsum[4];
  __shared__ int s_total;
  __shared__ int s_nu, s_ncert, s_out;
  __shared__ int   u_idx[UCAP];
  __shared__ float u_vf[UCAP];
  __shared__ unsigned char u_sel[UCAP];

  // -- binary search for the 64th-largest key bit pattern --
  unsigned cur = 0u;
  for (int bit = 31; bit >= 0; bit--) {
    const unsigned cand = cur | (1u << bit);
    int c = 0;
#pragma unroll
    for (int j = 0; j < 48; j++) c += (keys[j] >= cand) ? 1 : 0;
#pragma unroll
    for (int off = 32; off > 0; off >>= 1) c += __shfl_down(c, off);
    if (lane == 0) wsum[wid] = c;
    __syncthreads();
    if (tid == 0) s_total = wsum[0] + wsum[1] + wsum[2] + wsum[3];
    __syncthreads();
    if (s_total >= KTOP) cur = cand;
  }
  const float h64 = key_to_f32(cur);

  if (tid == 0) { s_nu = 0; s_ncert = 0; s_out = 0; }
  __syncthreads();

  // -- classify: certain (v > h64+m) / uncertain (|v-h64| <= m) / out --
  signed char uslot[48];
  int certc = 0;
#pragma unroll
  for (int j = 0; j < 48; j++) {
    const float v = key_to_f32(keys[j]);
    uslot[j] = -1;
    if (v > h64 + UMARGIN) {
      certc++;
    } else if (v >= h64 - UMARGIN) {
      int pos = atomicAdd(&s_nu, 1);
      if (pos < UCAP) {
        u_idx[pos] = tid + 256 * j;
        u_vf[pos]  = v;
        uslot[j] = (signed char)pos;
      }
    }
  }
  if (certc) atomicAdd(&s_ncert, certc);
  __syncthreads();

  const int nu = min(s_nu, UCAP);
  int t = KTOP - s_ncert;                 // open slots for uncertain set
  t = max(0, min(t, nu));

  if (nu > t) {
    // genuine contest: Model 1 — single sequential fp32 fmaf chain over all
    // of k (no blocking), bias added last.
    if (tid < nu) {
      const int ci = u_idx[tid];
      const float* xr = x + (size_t)row * DIN;
      float c = 0.0f;
      for (int k = 0; k < DIN; k++)
        c = fmaf(xr[k], We[(size_t)k * DLAT + ci], c);
      u_vf[tid] = c + b_enc[ci];
    }
    __syncthreads();
    // rank on sim values (no bitwise ties occur — r7 == r4 proved it)
    if (tid == 0) {
      for (int u = 0; u < nu; u++) {
        int rank = 0;
        for (int v2 = 0; v2 < nu; v2++)
          rank += (u_vf[v2] > u_vf[u]) ||
                  (u_vf[v2] == u_vf[u] && u_idx[v2] > u_idx[u]);
        u_sel[u] = (rank < t) ? 1 : 0;
      }
    }
  } else {
    // all uncertain elements are selected; approx values stand
    if (tid < nu) u_sel[tid] = 1;
  }
  __syncthreads();

  // -- final write: z row in place + compact (idx, val) lists --
#pragma unroll
  for (int j = 0; j < 48; j++) {
    const int idx = tid + 256 * j;
    const float v = key_to_f32(keys[j]);
    bool sel = false;
    float outv = 0.0f;
    if (v > h64 + UMARGIN) {
      sel = true; outv = v;
    } else if (uslot[j] >= 0 && u_sel[(int)uslot[j]]) {
      sel = true; outv = u_vf[(int)uslot[j]];
    }
    zr[idx] = sel ? outv : 0.0f;
    if (sel) {
      int s = atomicAdd(&s_out, 1);
      if (s < KTOP) {
        idxl[row * KTOP + s] = idx;
        vall[row * KTOP + s] = outv;
      }
    }
  }
}

// ---- sparse decoder: recon = z @ W_dec + b_dec (fp32) ----------------------
__global__ __launch_bounds__(192) void k_dec(const int* __restrict__ idxl,
                                             const float* __restrict__ vall,
                                             const float* __restrict__ Wd,
                                             const float* __restrict__ b_dec,
                                             float* __restrict__ R) {
  const int row = blockIdx.x;
  const int t = threadIdx.x;
  __shared__ int   sidx[KTOP];
  __shared__ float sval[KTOP];
  if (t < KTOP) {
    sidx[t] = idxl[row * KTOP + t];
    sval[t] = vall[row * KTOP + t];
  }
  __syncthreads();
  const int c = t * 4;
  float4 acc = *(const float4*)(b_dec + c);
#pragma unroll 4
  for (int j = 0; j < KTOP; j++) {
    float4 w = *(const float4*)(Wd + (size_t)sidx[j] * DIN + c);
    const float v = sval[j];
    acc.x += v * w.x;
    acc.y += v * w.y;
    acc.z += v * w.z;
    acc.w += v * w.w;
  }
  *(float4*)(R + (size_t)row * DIN + c) = acc;
}

// ----------------------------------------------------------------------------
extern "C" void kernel_launch(void* const* d_in, const int* in_sizes, int n_in,
                              void* d_out, int out_size, void* d_ws, size_t ws_size,
                              hipStream_t stream) {
  const float* x     = (const float*)d_in[0];
  const float* W_enc = (const float*)d_in[1];
  const float* b_enc = (const float*)d_in[2];
  const float* W_dec = (const float*)d_in[3];
  const float* b_dec = (const float*)d_in[4];

  float* recon = (float*)d_out;                       // [8192, 768]
  float* z     = (float*)d_out + (size_t)BROWS * DIN; // [8192, 12288] (doubles as h)

  // X fp16 split lives in the recon region (exact 25,165,824 B fit); consumed
  // by the GEMM, then overwritten by the decoder.
  unsigned short* Xh = (unsigned short*)recon;
  unsigned short* Xl = Xh + (size_t)BROWS * DIN;

  char* ws = (char*)d_ws;
  unsigned short* Wth = (unsigned short*)ws;                  // 18,874,368 B
  unsigned short* Wtl = (unsigned short*)(ws + 18874368);     // 18,874,368 B
  int*   idxl = (int*)(ws + 2 * 18874368);                    //  2,097,152 B
  float* vall = (float*)(ws + 2 * 18874368 + 2097152);        //  2,097,152 B

  k_cvt_split<<<6144, 256, 0, stream>>>(x, Xh, Xl, (BROWS * DIN) / 4);
  k_transpose_split<<<dim3(DLAT / 32, DIN / 32), dim3(32, 8), 0, stream>>>(W_enc, Wth, Wtl);
  k_enc_gemm<<<dim3(DLAT / BN, BROWS / BM), 256, 0, stream>>>(Xh, Xl, Wth, Wtl, b_enc, z);
  k_topk<<<BROWS, 256, 0, stream>>>(z, x, W_enc, b_enc, idxl, vall);
  k_dec<<<BROWS, 192, 0, stream>>>(idxl, vall, W_dec, b_dec, recon);
}